// Round 1
// baseline (223.515 us; speedup 1.0000x reference)
//
#include <hip/hip_runtime.h>
#include <math.h>

#define B_ 2
#define N_ 2048
#define E_ 1024
#define H_ 16
#define D_ 64

typedef unsigned short US;
typedef _Float16 h16x8 __attribute__((ext_vector_type(8)));
typedef _Float16 h16x4 __attribute__((ext_vector_type(4)));
typedef __fp16 fp16x2 __attribute__((ext_vector_type(2)));
typedef float f32x4 __attribute__((ext_vector_type(4)));
#define MFMA16F(a,b,c)  __builtin_amdgcn_mfma_f32_16x16x32_f16(a,b,c,0,0,0)
#define MFMA161(a,b,c)  __builtin_amdgcn_mfma_f32_16x16x16f16(a,b,c,0,0,0)
#define SCL  11.5415603828f   // 8 * log2(e), folded into Q at the QKV-GEMM epilogue

union HU { _Float16 h; US u; };
__device__ __forceinline__ US f2h(float f){ HU x; x.h = (_Float16)f; return x.u; }
__device__ __forceinline__ unsigned pkrtz(float a, float b){
  union { fp16x2 h; unsigned u; } x;
  x.h = __builtin_amdgcn_cvt_pkrtz(a, b);
  return x.u;
}

union U8 { US u[8]; uint4 v; };
union U4 { US u[4]; uint2 v; };
union UPA { unsigned u[2]; h16x4 h; };

// async global->LDS, 16B/lane; LDS dest = wave-uniform base + lane*16 (no padding possible)
__device__ __forceinline__ void glds16(const US* g, US* l){
  __builtin_amdgcn_global_load_lds(
    (const __attribute__((address_space(1))) unsigned int*)(const void*)g,
    (__attribute__((address_space(3))) unsigned int*)(void*)l, 16, 0, 0);
}

// ---- fused convert: x (2048 blocks) + Wq/Wk/Wv/Wo (512 blocks each) fp32->fp16 ----
__global__ __launch_bounds__(256) void conv_all(
    const float* __restrict__ x,
    const float* __restrict__ w0, const float* __restrict__ w1,
    const float* __restrict__ w2, const float* __restrict__ w3,
    US* __restrict__ xh, US* __restrict__ Wall)
{
  const int id = blockIdx.x;
  const float* s; US* d; size_t off;
  if (id < 2048) { s = x; d = xh; off = (size_t)id*2048; }
  else {
    int j = id - 2048, wsel = j>>9;
    off = (size_t)(j&511)*2048;
    s = (wsel==0)?w0:(wsel==1)?w1:(wsel==2)?w2:w3;
    d = Wall + (size_t)wsel*1048576;
  }
  size_t i = off + (size_t)threadIdx.x*8;
  float f[8];
  *(float4*)&f[0] = *(const float4*)&s[i];
  *(float4*)&f[4] = *(const float4*)&s[i+4];
  U8 h;
  #pragma unroll
  for (int j=0;j<8;++j) h.u[j] = f2h(f[j]);
  *(uint4*)&d[i] = h.v;
}

// ---- QKV GEMM, m97 geometry: 128x128 tile, BK=32, z-sliced (z selects Wq/Wk/Wv).
// Grid (8,32,3) = 768 blocks = exactly 3 blocks/CU at (256,3) -> single occupancy round.
// 4 waves, each 64x64 (4x4 frags); R/M = 16 MFMA : 8 ds_read_b128 = m97's proven ratio.
// Outputs: z=0 Q*SCL fp16 [B,H,N,D]; z=1 K fp16 [B,H,N,D]; z=2 V fp16 [B,H,D,N] (transposed).
__global__ __launch_bounds__(256,3) void qkv_gemm(
    const US* __restrict__ A, const US* __restrict__ Wall,
    const float* __restrict__ bq, const float* __restrict__ bk, const float* __restrict__ bv,
    US* __restrict__ Qf, US* __restrict__ Kf, US* __restrict__ Vtb)
{
  __shared__ __align__(16) US sA[128*32];
  __shared__ __align__(16) US sW[128*32];
  const int z = blockIdx.z;
  const US* W = Wall + (size_t)z*1048576;
  const float* bias = (z==0)?bq:(z==1)?bk:bv;

  const int t = threadIdx.x;
  const int w = t>>6, lane = t&63;
  const int q = lane>>4, c = lane&15;
  const int mq = (w>>1)*64, nq = (w&1)*64;
  const int gm0 = blockIdx.y*128, gn0 = blockIdx.x*128;
  const int r16 = lane>>2, seg = lane&3;    // staging: 4 lanes/row, 16B each

  f32x4 acc[4][4] = {};
  for (int kb = 0; kb < 1024; kb += 32) {
    #pragma unroll
    for (int p=0;p<2;++p){
      int rb = (w*2+p)*16;
      glds16(&A[(size_t)(gm0 + rb + r16)*1024 + kb + seg*8], &sA[rb*32]);
      glds16(&W[(size_t)(gn0 + rb + r16)*1024 + kb + seg*8], &sW[rb*32]);
    }
    __syncthreads();
    h16x8 af[4], wf[4];
    #pragma unroll
    for (int rt=0;rt<4;++rt) af[rt] = *(const h16x8*)&sA[(mq+rt*16+c)*32 + q*8];
    #pragma unroll
    for (int ct=0;ct<4;++ct) wf[ct] = *(const h16x8*)&sW[(nq+ct*16+c)*32 + q*8];
    #pragma unroll
    for (int rt=0;rt<4;++rt)
      #pragma unroll
      for (int ct=0;ct<4;++ct)
        acc[rt][ct] = MFMA16F(af[rt], wf[ct], acc[rt][ct]);
    __syncthreads();
  }
  #pragma unroll
  for (int rt=0;rt<4;++rt)
  #pragma unroll
  for (int ct=0;ct<4;++ct) {
    int col = gn0 + nq + ct*16 + c;
    float bv_ = bias[col];
    int rowb = gm0 + mq + rt*16 + q*4;
    int hh = col>>6, d = col & 63;
    if (z==2) {
      int b = rowb>>11, n = rowb & (N_-1);
      U4 pk;
      #pragma unroll
      for (int r=0;r<4;++r) pk.u[r] = f2h(acc[rt][ct][r] + bv_);
      *(uint2*)&Vtb[((size_t)(b*H_+hh)*D_ + d)*N_ + n] = pk.v;
    } else {
      US* dst = (z==0) ? Qf : Kf;
      #pragma unroll
      for (int r=0;r<4;++r) {
        int row = rowb + r;
        float v = acc[rt][ct][r] + bv_;
        if (z==0) v *= SCL;      // fold softmax scale + log2e into Q (fp32, pre-rounding)
        int b = row>>11, n = row & (N_-1);
        dst[((size_t)(b*H_+hh)*N_+n)*D_ + d] = f2h(v);
      }
    }
  }
}

// ---- O GEMM: out = H @ Wo^T + bo, fp32 row-major [4096][1024].
// 128M x 64N, BK=32; grid 16x32 = 512 = 2 blocks/CU at (256,4): single round.
__global__ __launch_bounds__(256,4) void o_gemm(
    const US* __restrict__ A, const US* __restrict__ W,
    const float* __restrict__ bias, float* __restrict__ out)
{
  __shared__ __align__(16) US sA[128*32];
  __shared__ __align__(16) US sW[64*32];
  const int t = threadIdx.x;
  const int w = t>>6, lane = t&63;
  const int q = lane>>4, c = lane&15;
  const int gm0 = blockIdx.y*128, gn0 = blockIdx.x*64;
  const int r16 = lane>>2, seg = lane&3;

  f32x4 acc[2][4] = {};
  for (int kb = 0; kb < 1024; kb += 32) {
    glds16(&A[(size_t)(gm0 + w*32      + r16)*1024 + kb + seg*8], &sA[(w*32)*32]);
    glds16(&A[(size_t)(gm0 + w*32 + 16 + r16)*1024 + kb + seg*8], &sA[(w*32+16)*32]);
    glds16(&W[(size_t)(gn0 + w*16      + r16)*1024 + kb + seg*8], &sW[(w*16)*32]);
    __syncthreads();
    h16x8 af0 = *(const h16x8*)&sA[(w*32+c)*32 + q*8];
    h16x8 af1 = *(const h16x8*)&sA[(w*32+16+c)*32 + q*8];
    #pragma unroll
    for (int ct=0; ct<4; ++ct){
      h16x8 wf = *(const h16x8*)&sW[(ct*16+c)*32 + q*8];
      acc[0][ct] = MFMA16F(af0, wf, acc[0][ct]);
      acc[1][ct] = MFMA16F(af1, wf, acc[1][ct]);
    }
    __syncthreads();
  }
  #pragma unroll
  for (int rt=0; rt<2; ++rt)
  #pragma unroll
  for (int ct=0; ct<4; ++ct) {
    int col = gn0 + ct*16 + c;
    float bv_ = bias[col];
    int rowb = gm0 + w*32 + rt*16 + q*4;
    #pragma unroll
    for (int r=0;r<4;++r)
      out[(size_t)(rowb+r)*1024 + col] = acc[rt][ct][r] + bv_;
  }
}

// ---- Flash attention: 512-thread blocks (8 waves), transposed-S, 128-key tiles.
// Wave w owns 16 q-rows (one qset as Q B-frags in regs, Q pre-scaled by 8*log2e).
//
// R10 change: PV (and the ones-row l accumulation) now use v_mfma_f32_16x16x16f16.
// The K=16 A-frag layout (lane holds A[row=lane&15][k=(lane>>4)*4+j] = keys 4q+j per
// 16-key step) EXACTLY matches the S^T C-layout (lane (q,c) holds keys 16f+4q+r for
// query c), so P feeds PV straight from registers: pa = {pkrtz(p0,p1), pkrtz(p2,p3)}.
// This deletes the per-wave sP buffer (34.8 KB) and its 12 LDS ops/wave-tile -> LDS
// 70656 -> 35840 B; with VGPR<=85 ((512,6)) occupancy goes 2 -> 3 blocks/CU (24 w/CU).
// V B-frags become 32x ds_read_b64 (<=2-way banked at VSTR=136). s_setprio(1) wraps
// the MFMA clusters (T5). Defer-max is UNSAFE here (logits *11.54 in exp2 domain,
// per-tile max jumps overflow fp16 P) -> classic per-tile max retained.
#define KSTR2 72   // K tile row stride
#define VSTR  136  // Vt row stride (128 keys + 8)
__global__ __launch_bounds__(512,6) void attn(
    const US* __restrict__ Qf, const US* __restrict__ Kf, const US* __restrict__ Vt,
    US* __restrict__ Hout)
{
  __shared__ __align__(16) US sK [128*KSTR2];
  __shared__ __align__(16) US sVt[64*VSTR];
  const int t = threadIdx.x;
  const int w = t>>6, lane = t&63, q = lane>>4, c = lane&15;
  const int id = blockIdx.x;
  // XCD swizzle: 16 q-tiles of one (b,h) stay on one XCD (id%8 stable across them)
  const int bh = ((id & 7) << 2) | ((id >> 3) & 3);
  const int n0 = (id >> 5) * 128;
  const US* Kp = Kf + (size_t)bh * (N_*D_);
  const US* Vp = Vt + (size_t)bh * (D_*N_);

  // Q B-frags in registers (pre-scaled): rows n0 + w*16 + c
  const size_t qoff = (size_t)bh*(N_*D_) + (size_t)(n0 + w*16 + c)*D_;
  h16x8 qb0 = *(const h16x8*)&Qf[qoff + q*8];
  h16x8 qb1 = *(const h16x8*)&Qf[qoff + 32 + q*8];
  h16x4 vones;
  #pragma unroll
  for (int j=0;j<4;++j) vones[j] = (_Float16)1.0f;

  float mi = -INFINITY;
  f32x4 o[5] = {};           // 0..3 = output d-cols; 4 = l accumulator (ones-row)

  const int kr = t>>3, kc8 = (t&7)*8;     // K staging: 8 thr/row, 64 rows/pass
  const int vr = t>>4, vc8 = (t&15)*8;    // Vt staging: 16 thr/row, 32 rows/pass

  for (int mt=0; mt<16; ++mt) {
    const int m0 = mt*128;
    #pragma unroll
    for (int p=0;p<2;++p){
      int r = p*64 + kr;
      *(uint4*)&sK[r*KSTR2 + kc8] = *(const uint4*)&Kp[(size_t)(m0 + r)*D_ + kc8];
    }
    #pragma unroll
    for (int p=0;p<2;++p){
      int r = p*32 + vr;
      *(uint4*)&sVt[r*VSTR + vc8] = *(const uint4*)&Vp[(size_t)r*N_ + m0 + vc8];
    }
    __syncthreads();

    // S^T: key f-frags (A=K rows f*16+c), qrow = B-col; already in exp2 domain
    f32x4 s[8];
    __builtin_amdgcn_s_setprio(1);
    #pragma unroll
    for (int f=0; f<8; ++f){
      h16x8 k0 = *(const h16x8*)&sK[(f*16+c)*KSTR2 + q*8];
      h16x8 k1 = *(const h16x8*)&sK[(f*16+c)*KSTR2 + 32 + q*8];
      f32x4 sv = {};
      sv = MFMA16F(k0, qb0, sv);
      sv = MFMA16F(k1, qb1, sv);
      s[f] = sv;
    }
    __builtin_amdgcn_s_setprio(0);

    // softmax: keys lane-local (32/lane); this lane's qrow = c
    f32x4 vm = s[0];
    #pragma unroll
    for (int f=1; f<8; ++f){
      vm[0]=fmaxf(vm[0],s[f][0]); vm[1]=fmaxf(vm[1],s[f][1]);
      vm[2]=fmaxf(vm[2],s[f][2]); vm[3]=fmaxf(vm[3],s[f][3]);
    }
    float v = fmaxf(fmaxf(vm[0],vm[1]), fmaxf(vm[2],vm[3]));
    v = fmaxf(v, __shfl_xor(v, 16));
    v = fmaxf(v, __shfl_xor(v, 32));     // replicated across the 4 q-lanes
    float mnew = fmaxf(mi, v);
    // alpha-skip: wave-uniform; max rarely updates after early tiles
    if (!__all(v <= mi)) {
      float alpha = exp2f(mi-mnew);
      float ar[4];
      #pragma unroll
      for (int r=0; r<4; ++r) ar[r] = __shfl(alpha, q*4+r);
      #pragma unroll
      for (int dt=0; dt<5; ++dt){        // includes the l accumulator
        o[dt][0]*=ar[0]; o[dt][1]*=ar[1]; o[dt][2]*=ar[2]; o[dt][3]*=ar[3];
      }
    }
    mi = mnew;
    // exp2 + pack P (rtz); P feeds PV directly as K=16 A-frags (keys 4q+j match the
    // S^T C-layout) -- no LDS round-trip. l comes from the ones-column MFMA.
    #pragma unroll
    for (int f=0; f<8; ++f){
      float p0 = exp2f(s[f][0]-mnew);
      float p1 = exp2f(s[f][1]-mnew);
      float p2 = exp2f(s[f][2]-mnew);
      float p3 = exp2f(s[f][3]-mnew);
      UPA pa;
      pa.u[0] = pkrtz(p0, p1);
      pa.u[1] = pkrtz(p2, p3);
      h16x4 pah = pa.h;
      __builtin_amdgcn_s_setprio(1);
      #pragma unroll
      for (int dt=0; dt<4; ++dt){
        h16x4 vf = *(const h16x4*)&sVt[(dt*16+c)*VSTR + f*16 + q*4];
        o[dt] = MFMA161(pah, vf, o[dt]);
      }
      o[4] = MFMA161(pah, vones, o[4]);
      __builtin_amdgcn_s_setprio(0);
    }
    __syncthreads();
  }

  // l is row-indexed (component r = row q*4+r): no shfl needed
  const int b = bh>>4, hh = bh&15;
  float ir[4];
  #pragma unroll
  for (int r=0; r<4; ++r) ir[r] = 1.0f / o[4][r];
  #pragma unroll
  for (int dt=0; dt<4; ++dt){
    #pragma unroll
    for (int r=0; r<4; ++r){
      int n = n0 + w*16 + q*4 + r;
      int d = dt*16 + c;
      Hout[((size_t)(b*N_+n)*H_+hh)*D_ + d] = f2h(o[dt][r] * ir[r]);  // [B,N,E] fp16
    }
  }
}

extern "C" void kernel_launch(void* const* d_in, const int* in_sizes, int n_in,
                              void* d_out, int out_size, void* d_ws, size_t ws_size,
                              hipStream_t stream)
{
  const float* x  = (const float*)d_in[0];
  const float* Wq = (const float*)d_in[1];
  const float* bq = (const float*)d_in[2];
  const float* Wk = (const float*)d_in[3];
  const float* bk = (const float*)d_in[4];
  const float* Wv = (const float*)d_in[5];
  const float* bv = (const float*)d_in[6];
  const float* Wo = (const float*)d_in[7];
  const float* bo = (const float*)d_in[8];
  US* ws  = (US*)d_ws;
  const size_t M1 = 1048576;
  US* xh   = ws;                 // 4M fp16
  US* Wall = ws + 4*M1;          // 4M: Wq,Wk,Wv,Wo fp16 contiguous
  US* Qf   = ws + 8*M1;          // 4M, [B,H,N,D], pre-scaled by 8*log2e
  US* Kf   = ws + 12*M1;         // 4M, [B,H,N,D]
  US* Vtb  = ws + 16*M1;         // 4M, [B,H,D,N]
  US* Hf   = ws + 20*M1;         // 4M, [B,N,E]  -> 48 MB total

  conv_all<<<4096, 256, 0, stream>>>(x, Wq, Wk, Wv, Wo, xh, Wall);
  qkv_gemm<<<dim3(8,32,3), 256, 0, stream>>>(xh, Wall, bq, bk, bv, Qf, Kf, Vtb);
  attn<<<512, 512, 0, stream>>>(Qf, Kf, Vtb, Hf);
  o_gemm<<<dim3(16,32), 256, 0, stream>>>(Hf, Wall + 3*M1, bo, (float*)d_out);
}

// Round 2
// 209.913 us; speedup vs baseline: 1.0648x; 1.0648x over previous
//
#include <hip/hip_runtime.h>
#include <math.h>

#define B_ 2
#define N_ 2048
#define E_ 1024
#define H_ 16
#define D_ 64

typedef unsigned short US;
typedef _Float16 h16x8 __attribute__((ext_vector_type(8)));
typedef _Float16 h16x4 __attribute__((ext_vector_type(4)));
typedef __fp16 fp16x2 __attribute__((ext_vector_type(2)));
typedef float f32x4 __attribute__((ext_vector_type(4)));
#define MFMA16F(a,b,c)  __builtin_amdgcn_mfma_f32_16x16x32_f16(a,b,c,0,0,0)
#define MFMA161(a,b,c)  __builtin_amdgcn_mfma_f32_16x16x16f16(a,b,c,0,0,0)
#define SCL  11.5415603828f   // 8 * log2(e), folded into Q at the QKV-GEMM epilogue

union HU { _Float16 h; US u; };
__device__ __forceinline__ US f2h(float f){ HU x; x.h = (_Float16)f; return x.u; }
__device__ __forceinline__ unsigned pkrtz(float a, float b){
  union { fp16x2 h; unsigned u; } x;
  x.h = __builtin_amdgcn_cvt_pkrtz(a, b);
  return x.u;
}

union U8 { US u[8]; uint4 v; };
union U4 { US u[4]; uint2 v; };
union UPA { unsigned u[2]; h16x4 h; };

// async global->LDS, 16B/lane; LDS dest = wave-uniform base + lane*16 (no padding possible)
__device__ __forceinline__ void glds16(const US* g, US* l){
  __builtin_amdgcn_global_load_lds(
    (const __attribute__((address_space(1))) unsigned int*)(const void*)g,
    (__attribute__((address_space(3))) unsigned int*)(void*)l, 16, 0, 0);
}

// ---- fused convert: x (2048 blocks) + Wq/Wk/Wv/Wo (512 blocks each) fp32->fp16 ----
__global__ __launch_bounds__(256) void conv_all(
    const float* __restrict__ x,
    const float* __restrict__ w0, const float* __restrict__ w1,
    const float* __restrict__ w2, const float* __restrict__ w3,
    US* __restrict__ xh, US* __restrict__ Wall)
{
  const int id = blockIdx.x;
  const float* s; US* d; size_t off;
  if (id < 2048) { s = x; d = xh; off = (size_t)id*2048; }
  else {
    int j = id - 2048, wsel = j>>9;
    off = (size_t)(j&511)*2048;
    s = (wsel==0)?w0:(wsel==1)?w1:(wsel==2)?w2:w3;
    d = Wall + (size_t)wsel*1048576;
  }
  size_t i = off + (size_t)threadIdx.x*8;
  float f[8];
  *(float4*)&f[0] = *(const float4*)&s[i];
  *(float4*)&f[4] = *(const float4*)&s[i+4];
  U8 h;
  #pragma unroll
  for (int j=0;j<8;++j) h.u[j] = f2h(f[j]);
  *(uint4*)&d[i] = h.v;
}

// ---- QKV GEMM, m97 geometry: 128x128 tile, BK=32, z-sliced (z selects Wq/Wk/Wv).
// Grid (8,32,3) = 768 blocks = exactly 3 blocks/CU at (256,3) -> single occupancy round.
// 4 waves, each 64x64 (4x4 frags); R/M = 16 MFMA : 8 ds_read_b128 = m97's proven ratio.
// Outputs: z=0 Q*SCL fp16 [B,H,N,D]; z=1 K fp16 [B,H,N,D]; z=2 V fp16 [B,H,D,N] (transposed).
__global__ __launch_bounds__(256,3) void qkv_gemm(
    const US* __restrict__ A, const US* __restrict__ Wall,
    const float* __restrict__ bq, const float* __restrict__ bk, const float* __restrict__ bv,
    US* __restrict__ Qf, US* __restrict__ Kf, US* __restrict__ Vtb)
{
  __shared__ __align__(16) US sA[128*32];
  __shared__ __align__(16) US sW[128*32];
  const int z = blockIdx.z;
  const US* W = Wall + (size_t)z*1048576;
  const float* bias = (z==0)?bq:(z==1)?bk:bv;

  const int t = threadIdx.x;
  const int w = t>>6, lane = t&63;
  const int q = lane>>4, c = lane&15;
  const int mq = (w>>1)*64, nq = (w&1)*64;
  const int gm0 = blockIdx.y*128, gn0 = blockIdx.x*128;
  const int r16 = lane>>2, seg = lane&3;    // staging: 4 lanes/row, 16B each

  f32x4 acc[4][4] = {};
  for (int kb = 0; kb < 1024; kb += 32) {
    #pragma unroll
    for (int p=0;p<2;++p){
      int rb = (w*2+p)*16;
      glds16(&A[(size_t)(gm0 + rb + r16)*1024 + kb + seg*8], &sA[rb*32]);
      glds16(&W[(size_t)(gn0 + rb + r16)*1024 + kb + seg*8], &sW[rb*32]);
    }
    __syncthreads();
    h16x8 af[4], wf[4];
    #pragma unroll
    for (int rt=0;rt<4;++rt) af[rt] = *(const h16x8*)&sA[(mq+rt*16+c)*32 + q*8];
    #pragma unroll
    for (int ct=0;ct<4;++ct) wf[ct] = *(const h16x8*)&sW[(nq+ct*16+c)*32 + q*8];
    #pragma unroll
    for (int rt=0;rt<4;++rt)
      #pragma unroll
      for (int ct=0;ct<4;++ct)
        acc[rt][ct] = MFMA16F(af[rt], wf[ct], acc[rt][ct]);
    __syncthreads();
  }
  #pragma unroll
  for (int rt=0;rt<4;++rt)
  #pragma unroll
  for (int ct=0;ct<4;++ct) {
    int col = gn0 + nq + ct*16 + c;
    float bv_ = bias[col];
    int rowb = gm0 + mq + rt*16 + q*4;
    int hh = col>>6, d = col & 63;
    if (z==2) {
      int b = rowb>>11, n = rowb & (N_-1);
      U4 pk;
      #pragma unroll
      for (int r=0;r<4;++r) pk.u[r] = f2h(acc[rt][ct][r] + bv_);
      *(uint2*)&Vtb[((size_t)(b*H_+hh)*D_ + d)*N_ + n] = pk.v;
    } else {
      US* dst = (z==0) ? Qf : Kf;
      #pragma unroll
      for (int r=0;r<4;++r) {
        int row = rowb + r;
        float v = acc[rt][ct][r] + bv_;
        if (z==0) v *= SCL;      // fold softmax scale + log2e into Q (fp32, pre-rounding)
        int b = row>>11, n = row & (N_-1);
        dst[((size_t)(b*H_+hh)*N_+n)*D_ + d] = f2h(v);
      }
    }
  }
}

// ---- O GEMM: out = H @ Wo^T + bo, fp32 row-major [4096][1024].
// 128M x 64N, BK=32; grid 16x32 = 512 = 2 blocks/CU at (256,4): single round.
__global__ __launch_bounds__(256,4) void o_gemm(
    const US* __restrict__ A, const US* __restrict__ W,
    const float* __restrict__ bias, float* __restrict__ out)
{
  __shared__ __align__(16) US sA[128*32];
  __shared__ __align__(16) US sW[64*32];
  const int t = threadIdx.x;
  const int w = t>>6, lane = t&63;
  const int q = lane>>4, c = lane&15;
  const int gm0 = blockIdx.y*128, gn0 = blockIdx.x*64;
  const int r16 = lane>>2, seg = lane&3;

  f32x4 acc[2][4] = {};
  for (int kb = 0; kb < 1024; kb += 32) {
    glds16(&A[(size_t)(gm0 + w*32      + r16)*1024 + kb + seg*8], &sA[(w*32)*32]);
    glds16(&A[(size_t)(gm0 + w*32 + 16 + r16)*1024 + kb + seg*8], &sA[(w*32+16)*32]);
    glds16(&W[(size_t)(gn0 + w*16      + r16)*1024 + kb + seg*8], &sW[(w*16)*32]);
    __syncthreads();
    h16x8 af0 = *(const h16x8*)&sA[(w*32+c)*32 + q*8];
    h16x8 af1 = *(const h16x8*)&sA[(w*32+16+c)*32 + q*8];
    #pragma unroll
    for (int ct=0; ct<4; ++ct){
      h16x8 wf = *(const h16x8*)&sW[(ct*16+c)*32 + q*8];
      acc[0][ct] = MFMA16F(af0, wf, acc[0][ct]);
      acc[1][ct] = MFMA16F(af1, wf, acc[1][ct]);
    }
    __syncthreads();
  }
  #pragma unroll
  for (int rt=0; rt<2; ++rt)
  #pragma unroll
  for (int ct=0; ct<4; ++ct) {
    int col = gn0 + ct*16 + c;
    float bv_ = bias[col];
    int rowb = gm0 + w*32 + rt*16 + q*4;
    #pragma unroll
    for (int r=0;r<4;++r)
      out[(size_t)(rowb+r)*1024 + col] = acc[rt][ct][r] + bv_;
  }
}

// ---- Flash attention: 512-thread blocks (8 waves), transposed-S, 128-key tiles.
// Wave w owns 16 q-rows (Q as B-frags in regs, pre-scaled by 8*log2e).
//
// R11: keep R10's register-P PV (K=16 v_mfma_f32_16x16x16f16: its A-frag key layout
// 4q+j matches the S^T C-layout exactly, so P never touches LDS). Spend the freed
// 34.8 KB on DOUBLE-BUFFERED K/V (71.7 KB total, still 2 blocks/CU -- grid=512 caps
// residency at 2 blocks/CU anyway). T14 async-split staging: next tile's
// global_load_dwordx4 issued at loop top into regs (latency hides under QK+softmax+PV),
// ds_write into buf^1 after compute, ONE barrier per iteration (buf^1 was last read in
// iter mt-1 whose trailing barrier already fenced it).
// R10 post-mortem: (512,6) squeezed unified VGPR+AGPR to ~85 < ~95 demand -> ~16 MB
// scratch spill traffic (FETCH +5.1 MB, WRITE +10.7 MB). Restored to (512,4).
// Defer-max stays OFF (logits *11.54 in exp2 domain; fp16 P would overflow).
#define KSTR2 72   // K tile row stride
#define VSTR  136  // Vt row stride (128 keys + 8)
__global__ __launch_bounds__(512,4) void attn(
    const US* __restrict__ Qf, const US* __restrict__ Kf, const US* __restrict__ Vt,
    US* __restrict__ Hout)
{
  __shared__ __align__(16) US sK [2][128*KSTR2];
  __shared__ __align__(16) US sVt[2][64*VSTR];
  const int t = threadIdx.x;
  const int w = t>>6, lane = t&63, q = lane>>4, c = lane&15;
  const int id = blockIdx.x;
  // XCD swizzle: 16 q-tiles of one (b,h) stay on one XCD (id%8 stable across them)
  const int bh = ((id & 7) << 2) | ((id >> 3) & 3);
  const int n0 = (id >> 5) * 128;
  const US* Kp = Kf + (size_t)bh * (N_*D_);
  const US* Vp = Vt + (size_t)bh * (D_*N_);

  // Q B-frags in registers (pre-scaled): rows n0 + w*16 + c
  const size_t qoff = (size_t)bh*(N_*D_) + (size_t)(n0 + w*16 + c)*D_;
  h16x8 qb0 = *(const h16x8*)&Qf[qoff + q*8];
  h16x8 qb1 = *(const h16x8*)&Qf[qoff + 32 + q*8];
  h16x4 vones;
  #pragma unroll
  for (int j=0;j<4;++j) vones[j] = (_Float16)1.0f;

  float mi = -INFINITY;
  f32x4 o[5] = {};           // 0..3 = output d-cols; 4 = l accumulator (ones-row)

  const int kr = t>>3, kc8 = (t&7)*8;     // K staging: 8 thr/row, 64 rows/pass
  const int vr = t>>4, vc8 = (t&15)*8;    // Vt staging: 16 thr/row, 32 rows/pass

  // prologue: stage tile 0 into buffer 0
  #pragma unroll
  for (int p=0;p<2;++p){
    int r = p*64 + kr;
    *(uint4*)&sK[0][r*KSTR2 + kc8] = *(const uint4*)&Kp[(size_t)r*D_ + kc8];
  }
  #pragma unroll
  for (int p=0;p<2;++p){
    int r = p*32 + vr;
    *(uint4*)&sVt[0][r*VSTR + vc8] = *(const uint4*)&Vp[(size_t)r*N_ + vc8];
  }
  __syncthreads();

  for (int mt=0; mt<16; ++mt) {
    const int cur = mt&1;
    // T14 issue-early: next tile's global loads into regs; vmcnt waited only at the
    // ds_write at the bottom -- QK+softmax+PV covers the latency.
    uint4 kreg[2], vreg[2];
    if (mt < 15){
      const int m1 = (mt+1)*128;
      #pragma unroll
      for (int p=0;p<2;++p)
        kreg[p] = *(const uint4*)&Kp[(size_t)(m1 + p*64 + kr)*D_ + kc8];
      #pragma unroll
      for (int p=0;p<2;++p)
        vreg[p] = *(const uint4*)&Vp[(size_t)(p*32 + vr)*N_ + m1 + vc8];
    }

    // S^T: key f-frags (A=K rows f*16+c), qrow = B-col; already in exp2 domain
    f32x4 s[8];
    __builtin_amdgcn_s_setprio(1);
    #pragma unroll
    for (int f=0; f<8; ++f){
      h16x8 k0 = *(const h16x8*)&sK[cur][(f*16+c)*KSTR2 + q*8];
      h16x8 k1 = *(const h16x8*)&sK[cur][(f*16+c)*KSTR2 + 32 + q*8];
      f32x4 sv = {};
      sv = MFMA16F(k0, qb0, sv);
      sv = MFMA16F(k1, qb1, sv);
      s[f] = sv;
    }
    __builtin_amdgcn_s_setprio(0);

    // softmax: keys lane-local (32/lane); this lane's qrow = c
    f32x4 vm = s[0];
    #pragma unroll
    for (int f=1; f<8; ++f){
      vm[0]=fmaxf(vm[0],s[f][0]); vm[1]=fmaxf(vm[1],s[f][1]);
      vm[2]=fmaxf(vm[2],s[f][2]); vm[3]=fmaxf(vm[3],s[f][3]);
    }
    float v = fmaxf(fmaxf(vm[0],vm[1]), fmaxf(vm[2],vm[3]));
    v = fmaxf(v, __shfl_xor(v, 16));
    v = fmaxf(v, __shfl_xor(v, 32));     // replicated across the 4 q-lanes
    float mnew = fmaxf(mi, v);
    // alpha-skip: wave-uniform; max rarely updates after early tiles
    if (!__all(v <= mi)) {
      float alpha = exp2f(mi-mnew);
      float ar[4];
      #pragma unroll
      for (int r=0; r<4; ++r) ar[r] = __shfl(alpha, q*4+r);
      #pragma unroll
      for (int dt=0; dt<5; ++dt){        // includes the l accumulator
        o[dt][0]*=ar[0]; o[dt][1]*=ar[1]; o[dt][2]*=ar[2]; o[dt][3]*=ar[3];
      }
    }
    mi = mnew;
    // exp2 + pack P (rtz); P feeds PV directly as K=16 A-frags (keys 4q+j match the
    // S^T C-layout) -- no LDS round-trip. l comes from the ones-column MFMA.
    #pragma unroll
    for (int f=0; f<8; ++f){
      float p0 = exp2f(s[f][0]-mnew);
      float p1 = exp2f(s[f][1]-mnew);
      float p2 = exp2f(s[f][2]-mnew);
      float p3 = exp2f(s[f][3]-mnew);
      UPA pa;
      pa.u[0] = pkrtz(p0, p1);
      pa.u[1] = pkrtz(p2, p3);
      h16x4 pah = pa.h;
      __builtin_amdgcn_s_setprio(1);
      #pragma unroll
      for (int dt=0; dt<4; ++dt){
        h16x4 vf = *(const h16x4*)&sVt[cur][(dt*16+c)*VSTR + f*16 + q*4];
        o[dt] = MFMA161(pah, vf, o[dt]);
      }
      o[4] = MFMA161(pah, vones, o[4]);
      __builtin_amdgcn_s_setprio(0);
    }

    // T14 write-late: land next tile in buf^1 (last read in iter mt-1; its trailing
    // barrier already fenced it -- no extra barrier needed before these writes).
    if (mt < 15){
      #pragma unroll
      for (int p=0;p<2;++p)
        *(uint4*)&sK[cur^1][(p*64+kr)*KSTR2 + kc8] = kreg[p];
      #pragma unroll
      for (int p=0;p<2;++p)
        *(uint4*)&sVt[cur^1][(p*32+vr)*VSTR + vc8] = vreg[p];
    }
    __syncthreads();
  }

  // l is row-indexed (component r = row q*4+r): no shfl needed
  const int b = bh>>4, hh = bh&15;
  float ir[4];
  #pragma unroll
  for (int r=0; r<4; ++r) ir[r] = 1.0f / o[4][r];
  #pragma unroll
  for (int dt=0; dt<4; ++dt){
    #pragma unroll
    for (int r=0; r<4; ++r){
      int n = n0 + w*16 + q*4 + r;
      int d = dt*16 + c;
      Hout[((size_t)(b*N_+n)*H_+hh)*D_ + d] = f2h(o[dt][r] * ir[r]);  // [B,N,E] fp16
    }
  }
}

extern "C" void kernel_launch(void* const* d_in, const int* in_sizes, int n_in,
                              void* d_out, int out_size, void* d_ws, size_t ws_size,
                              hipStream_t stream)
{
  const float* x  = (const float*)d_in[0];
  const float* Wq = (const float*)d_in[1];
  const float* bq = (const float*)d_in[2];
  const float* Wk = (const float*)d_in[3];
  const float* bk = (const float*)d_in[4];
  const float* Wv = (const float*)d_in[5];
  const float* bv = (const float*)d_in[6];
  const float* Wo = (const float*)d_in[7];
  const float* bo = (const float*)d_in[8];
  US* ws  = (US*)d_ws;
  const size_t M1 = 1048576;
  US* xh   = ws;                 // 4M fp16
  US* Wall = ws + 4*M1;          // 4M: Wq,Wk,Wv,Wo fp16 contiguous
  US* Qf   = ws + 8*M1;          // 4M, [B,H,N,D], pre-scaled by 8*log2e
  US* Kf   = ws + 12*M1;         // 4M, [B,H,N,D]
  US* Vtb  = ws + 16*M1;         // 4M, [B,H,D,N]
  US* Hf   = ws + 20*M1;         // 4M, [B,N,E]  -> 48 MB total

  conv_all<<<4096, 256, 0, stream>>>(x, Wq, Wk, Wv, Wo, xh, Wall);
  qkv_gemm<<<dim3(8,32,3), 256, 0, stream>>>(xh, Wall, bq, bk, bv, Qf, Kf, Vtb);
  attn<<<512, 512, 0, stream>>>(Qf, Kf, Vtb, Hf);
  o_gemm<<<dim3(16,32), 256, 0, stream>>>(Hf, Wall + 3*M1, bo, (float*)d_out);
}